// Round 6
// baseline (328.564 us; speedup 1.0000x reference)
//
#include <hip/hip_runtime.h>
#include <cstdint>
#include <cstddef>

#define NNODES 100000
#define NEDGES 1600000
#define NGRAPHS 64
#define BSHIFT 8
#define BRANGE 256
#define NB 391  // ceil(NNODES / 256)

typedef short short8v __attribute__((ext_vector_type(8)));
typedef float float4v __attribute__((ext_vector_type(4)));

__device__ inline ushort f2bf(float f) {
    uint u = __float_as_uint(f);
    return (ushort)((u + 0x7fffu + ((u >> 16) & 1u)) >> 16);
}
__device__ inline uint pack2(float lo, float hi) {
    return (uint)f2bf(lo) | ((uint)f2bf(hi) << 16);
}
__device__ inline float bflo(uint u) { return __uint_as_float(u << 16); }
__device__ inline float bfhi(uint u) { return __uint_as_float(u & 0xffff0000u); }

// ---------------- utils ----------------

__global__ void k_zero_int(int* p, int n) {
    int i = blockIdx.x * blockDim.x + threadIdx.x;
    if (i < n) p[i] = 0;
}

// ---------------- CSR build (bucketed, LDS-aggregated) ----------------

__global__ __launch_bounds__(256) void k_bcount(const int* __restrict__ dst,
                                                int* __restrict__ bcnt, int E) {
    __shared__ int h[NB];
    for (int i = threadIdx.x; i < NB; i += 256) h[i] = 0;
    __syncthreads();
    for (int e = blockIdx.x * 256 + threadIdx.x; e < E; e += gridDim.x * 256)
        atomicAdd(&h[dst[e] >> BSHIFT], 1);
    __syncthreads();
    for (int i = threadIdx.x; i < NB; i += 256)
        if (h[i]) atomicAdd(&bcnt[i], h[i]);
}

__global__ __launch_bounds__(512) void k_bscan(const int* __restrict__ bcnt,
                                               int* __restrict__ boffs,
                                               int* __restrict__ bcur) {
    __shared__ int sh[512];
    int t = threadIdx.x;
    int v = t < NB ? bcnt[t] : 0;
    sh[t] = v;
    __syncthreads();
    #pragma unroll
    for (int d = 1; d < 512; d <<= 1) {
        int val = (t >= d) ? sh[t - d] : 0;
        __syncthreads();
        sh[t] += val;
        __syncthreads();
    }
    int excl = sh[t] - v;
    if (t < NB) { boffs[t] = excl; bcur[t] = excl; }
    if (t == NB - 1) boffs[NB] = excl + v;
}

// P1: scatter packed (src | (dst&255)<<24) into bucket-grouped order.
#define P1_EPT 8
__global__ __launch_bounds__(256) void k_bscatter(const int* __restrict__ src,
                                                  const int* __restrict__ dst,
                                                  int* __restrict__ bcur,
                                                  uint* __restrict__ pairs, int E) {
    __shared__ int h[NB];
    __shared__ int base[NB];
    int t = threadIdx.x;
    long long c0 = (long long)blockIdx.x * 2048;
    if (c0 >= E) return;
    for (int i = t; i < NB; i += 256) h[i] = 0;
    __syncthreads();
    int myb[P1_EPT], mylp[P1_EPT];
    uint myv[P1_EPT];
    #pragma unroll
    for (int k = 0; k < P1_EPT; ++k) {
        long long e = c0 + t + k * 256;
        if (e < E) {
            int d = dst[e];
            myv[k] = (uint)src[e] | ((uint)(d & (BRANGE - 1)) << 24);
            myb[k] = d >> BSHIFT;
            mylp[k] = atomicAdd(&h[myb[k]], 1);
        } else myb[k] = -1;
    }
    __syncthreads();
    for (int i = t; i < NB; i += 256)
        base[i] = h[i] ? atomicAdd(&bcur[i], h[i]) : 0;
    __syncthreads();
    #pragma unroll
    for (int k = 0; k < P1_EPT; ++k)
        if (myb[k] >= 0) pairs[base[myb[k]] + mylp[k]] = myv[k];
}

// per-bucket node in-degree histogram + dinv (fused)
__global__ __launch_bounds__(256) void k_nodecnt(const uint* __restrict__ pairs,
                                                 const int* __restrict__ boffs,
                                                 int* __restrict__ cnt,
                                                 float* __restrict__ dinv, int N) {
    __shared__ int h[BRANGE];
    int b = blockIdx.x, t = threadIdx.x;
    h[t] = 0;
    __syncthreads();
    int p0 = boffs[b], p1 = boffs[b + 1];
    for (int p = p0 + t; p < p1; p += 256)
        atomicAdd(&h[pairs[p] >> 24], 1);
    __syncthreads();
    int node = (b << BSHIFT) + t;
    if (node < N) {
        cnt[node] = h[t];
        dinv[node] = rsqrtf((float)(h[t] + 1));
    }
}

__global__ __launch_bounds__(256) void k_csr(const uint* __restrict__ pairs,
                                             const int* __restrict__ boffs,
                                             const int* __restrict__ offs,
                                             int* __restrict__ csr, int N) {
    __shared__ int cur[BRANGE];
    int b = blockIdx.x, t = threadIdx.x;
    int node = (b << BSHIFT) + t;
    cur[t] = node < N ? offs[node] : 0;
    __syncthreads();
    int p0 = boffs[b], p1 = boffs[b + 1];
    for (int p = p0 + t; p < p1; p += 256) {
        uint pr = pairs[p];
        int pos = atomicAdd(&cur[pr >> 24], 1);
        csr[pos] = (int)(pr & 0x00FFFFFFu);
    }
}

// ---------------- node-count exclusive scan ----------------

__global__ __launch_bounds__(256) void k_scan_local(const int* __restrict__ cnt,
                                                    int* __restrict__ offs,
                                                    int* __restrict__ bsums, int n) {
    __shared__ int sh[256];
    int t = threadIdx.x;
    int base = blockIdx.x * 1024 + t * 4;
    int v0 = base + 0 < n ? cnt[base + 0] : 0;
    int v1 = base + 1 < n ? cnt[base + 1] : 0;
    int v2 = base + 2 < n ? cnt[base + 2] : 0;
    int v3 = base + 3 < n ? cnt[base + 3] : 0;
    int tsum = v0 + v1 + v2 + v3;
    sh[t] = tsum;
    __syncthreads();
    #pragma unroll
    for (int d = 1; d < 256; d <<= 1) {
        int val = (t >= d) ? sh[t - d] : 0;
        __syncthreads();
        sh[t] += val;
        __syncthreads();
    }
    int excl = sh[t] - tsum;
    if (t == 255) bsums[blockIdx.x] = sh[255];
    if (base + 0 < n) offs[base + 0] = excl;
    if (base + 1 < n) offs[base + 1] = excl + v0;
    if (base + 2 < n) offs[base + 2] = excl + v0 + v1;
    if (base + 3 < n) offs[base + 3] = excl + v0 + v1 + v2;
}

__global__ __launch_bounds__(256) void k_scan_bsums(int* bsums, int nb) {
    __shared__ int sh[256];
    int t = threadIdx.x;
    int v = t < nb ? bsums[t] : 0;
    sh[t] = v;
    __syncthreads();
    #pragma unroll
    for (int d = 1; d < 256; d <<= 1) {
        int val = (t >= d) ? sh[t - d] : 0;
        __syncthreads();
        sh[t] += val;
        __syncthreads();
    }
    if (t < nb) bsums[t] = sh[t] - v;
}

// scan finalize + graph segment bounds (fused)
__global__ void k_scan_add_bounds(int* __restrict__ offs, const int* __restrict__ bsums,
                                  const int* __restrict__ batch, int* __restrict__ gstart,
                                  int* __restrict__ gend, int n) {
    int i = blockIdx.x * blockDim.x + threadIdx.x;
    if (i < n) {
        offs[i] += bsums[i >> 10];
        int b = batch[i];
        if (i == 0 || batch[i - 1] != b) gstart[b] = i;
        if (i == n - 1 || batch[i + 1] != b) gend[b] = i + 1;
    }
    if (i == 0) offs[n] = NEDGES;
}

// ---------------- MFMA GEMM: msg_bf16[n,128] = (X[n,128] @ W[128,128]) * dinv[row] ----

__global__ __launch_bounds__(256) void k_gemm_f32(const float* __restrict__ X,
                                                  const float* __restrict__ W,
                                                  const float* __restrict__ dinv,
                                                  ushort* __restrict__ Y, int nrows) {
    __shared__ short8v sW[2048];  // [kk(4)][ct(8)][lane(64)]
    const int tid = threadIdx.x;
    const int lane = tid & 63;
    const int w = tid >> 6;

    for (int s = tid; s < 2048; s += 256) {
        int p = s >> 6, l = s & 63;
        int kk = p >> 3, ct = p & 7;
        int kb = kk * 32 + (l >> 4) * 8;
        int j = ct * 16 + (l & 15);
        short8v v;
        #pragma unroll
        for (int i = 0; i < 8; ++i)
            v[i] = (short)f2bf(W[(size_t)(kb + i) * 128 + j]);
        sW[s] = v;
    }
    __syncthreads();

    const int row0 = blockIdx.x * 64 + w * 16;
    const int arow = row0 + (lane & 15);
    float4v acc[8];
    #pragma unroll
    for (int ct = 0; ct < 8; ++ct) acc[ct] = (float4v)0.f;

    #pragma unroll
    for (int kk = 0; kk < 4; ++kk) {
        short8v a = (short8v)0;
        if (arow < nrows) {
            const float* xp = X + (size_t)arow * 128 + kk * 32 + ((lane >> 4) * 8);
            float4 f0 = ((const float4*)xp)[0];
            float4 f1 = ((const float4*)xp)[1];
            a[0] = (short)f2bf(f0.x); a[1] = (short)f2bf(f0.y);
            a[2] = (short)f2bf(f0.z); a[3] = (short)f2bf(f0.w);
            a[4] = (short)f2bf(f1.x); a[5] = (short)f2bf(f1.y);
            a[6] = (short)f2bf(f1.z); a[7] = (short)f2bf(f1.w);
        }
        #pragma unroll
        for (int ct = 0; ct < 8; ++ct)
            acc[ct] = __builtin_amdgcn_mfma_f32_16x16x32_bf16(a, sW[(kk * 8 + ct) * 64 + lane],
                                                              acc[ct], 0, 0, 0);
    }

    const int orow = row0 + ((lane >> 4) << 2);
    #pragma unroll
    for (int r = 0; r < 4; ++r) {
        int row = orow + r;
        if (row < nrows) {
            float dr = dinv[row];
            #pragma unroll
            for (int ct = 0; ct < 8; ++ct)
                Y[(size_t)row * 128 + ct * 16 + (lane & 15)] = f2bf(acc[ct][r] * dr);
        }
    }
}

// bf16-input variant (layer 2)
__global__ __launch_bounds__(256) void k_gemm_b16(const ushort* __restrict__ X,
                                                  const float* __restrict__ W,
                                                  const float* __restrict__ dinv,
                                                  ushort* __restrict__ Y, int nrows) {
    __shared__ short8v sW[2048];
    const int tid = threadIdx.x;
    const int lane = tid & 63;
    const int w = tid >> 6;

    for (int s = tid; s < 2048; s += 256) {
        int p = s >> 6, l = s & 63;
        int kk = p >> 3, ct = p & 7;
        int kb = kk * 32 + (l >> 4) * 8;
        int j = ct * 16 + (l & 15);
        short8v v;
        #pragma unroll
        for (int i = 0; i < 8; ++i)
            v[i] = (short)f2bf(W[(size_t)(kb + i) * 128 + j]);
        sW[s] = v;
    }
    __syncthreads();

    const int row0 = blockIdx.x * 64 + w * 16;
    const int arow = row0 + (lane & 15);
    float4v acc[8];
    #pragma unroll
    for (int ct = 0; ct < 8; ++ct) acc[ct] = (float4v)0.f;

    #pragma unroll
    for (int kk = 0; kk < 4; ++kk) {
        short8v a = (short8v)0;
        if (arow < nrows)
            a = *(const short8v*)(X + (size_t)arow * 128 + kk * 32 + ((lane >> 4) * 8));
        #pragma unroll
        for (int ct = 0; ct < 8; ++ct)
            acc[ct] = __builtin_amdgcn_mfma_f32_16x16x32_bf16(a, sW[(kk * 8 + ct) * 64 + lane],
                                                              acc[ct], 0, 0, 0);
    }

    const int orow = row0 + ((lane >> 4) << 2);
    #pragma unroll
    for (int r = 0; r < 4; ++r) {
        int row = orow + r;
        if (row < nrows) {
            float dr = dinv[row];
            #pragma unroll
            for (int ct = 0; ct < 8; ++ct)
                Y[(size_t)row * 128 + ct * 16 + (lane & 15)] = f2bf(acc[ct][r] * dr);
        }
    }
}

// ---------------- CSR aggregation: wave/node, batch-32 deep-MLP gathers ----------------
// h[i,:] = relu( dinv[i] * (msg[i,:] + sum_{s in in(i)} msg[s,:]) + bias )

__global__ __launch_bounds__(256) void k_agg(const uint4* __restrict__ msg,
                                             const float* __restrict__ dinv,
                                             const int* __restrict__ offs,
                                             const int* __restrict__ csr,
                                             const float* __restrict__ bias,
                                             uint4* __restrict__ outb, int n, int dorelu) {
    int wid = (int)((blockIdx.x * 256 + threadIdx.x) >> 6);
    if (wid >= n) return;
    const int lane = threadIdx.x & 63;
    const int q = lane >> 4, c = lane & 15;
    float acc[8];
    {   // self contribution (weight 1) counted once, in q==0
        uint4 u = msg[(size_t)wid * 16 + c];
        float m = (q == 0) ? 1.f : 0.f;
        acc[0] = bflo(u.x) * m; acc[1] = bfhi(u.x) * m;
        acc[2] = bflo(u.y) * m; acc[3] = bfhi(u.y) * m;
        acc[4] = bflo(u.z) * m; acc[5] = bfhi(u.z) * m;
        acc[6] = bflo(u.w) * m; acc[7] = bfhi(u.w) * m;
    }
    const int e0 = offs[wid], e1 = offs[wid + 1];
    for (int base = e0; base < e1; base += 32) {
        int idx[8];
        float mk[8];
        // 1) all indices first (clamped; excess slots re-read last neighbor, L1-hot)
        #pragma unroll
        for (int j = 0; j < 8; ++j) {
            int p = base + q + 4 * j;
            idx[j] = csr[min(p, e1 - 1)];
            mk[j] = (p < e1) ? 1.f : 0.f;
        }
        // 2) all gathers issued back-to-back (8 outstanding per lane)
        uint4 g[8];
        #pragma unroll
        for (int j = 0; j < 8; ++j)
            g[j] = msg[(size_t)idx[j] * 16 + c];
        // 3) unpack + FMA
        #pragma unroll
        for (int j = 0; j < 8; ++j) {
            acc[0] = fmaf(bflo(g[j].x), mk[j], acc[0]);
            acc[1] = fmaf(bfhi(g[j].x), mk[j], acc[1]);
            acc[2] = fmaf(bflo(g[j].y), mk[j], acc[2]);
            acc[3] = fmaf(bfhi(g[j].y), mk[j], acc[3]);
            acc[4] = fmaf(bflo(g[j].z), mk[j], acc[4]);
            acc[5] = fmaf(bfhi(g[j].z), mk[j], acc[5]);
            acc[6] = fmaf(bflo(g[j].w), mk[j], acc[6]);
            acc[7] = fmaf(bfhi(g[j].w), mk[j], acc[7]);
        }
    }
    #pragma unroll
    for (int j = 0; j < 8; ++j) {
        acc[j] += __shfl_xor(acc[j], 16);
        acc[j] += __shfl_xor(acc[j], 32);
    }
    if (q == 0) {
        float dd = dinv[wid];
        #pragma unroll
        for (int j = 0; j < 8; ++j) {
            acc[j] *= dd;
            if (bias) acc[j] += bias[c * 8 + j];
            if (dorelu) acc[j] = fmaxf(acc[j], 0.f);
        }
        uint4 o;
        o.x = pack2(acc[0], acc[1]);
        o.y = pack2(acc[2], acc[3]);
        o.z = pack2(acc[4], acc[5]);
        o.w = pack2(acc[6], acc[7]);
        outb[(size_t)wid * 16 + c] = o;
    }
}

// ---------------- pooling (bf16 input) ----------------

__global__ __launch_bounds__(128) void k_pool16(const uint* __restrict__ buf,
                                                const int* __restrict__ gstart,
                                                const int* __restrict__ gend,
                                                float* __restrict__ sums) {
    int g = blockIdx.x, chunk = blockIdx.y;
    int s = gstart[g], e = gend[g];
    int per = (e - s + 7) >> 3;
    int r0 = s + chunk * per, r1 = min(e, r0 + per);
    int j = threadIdx.x & 63, half = threadIdx.x >> 6;
    float ax = 0.f, ay = 0.f;
    for (int r = r0 + half; r < r1; r += 2) {
        uint u = buf[(size_t)r * 64 + j];
        ax += bflo(u);
        ay += bfhi(u);
    }
    atomicAdd(&sums[g * 128 + 2 * j], ax);
    atomicAdd(&sums[g * 128 + 2 * j + 1], ay);
}

__global__ void k_final(const float* __restrict__ sums, const int* __restrict__ gstart,
                        const int* __restrict__ gend, const float* __restrict__ b2,
                        const float* __restrict__ linW, const float* __restrict__ linb,
                        float* __restrict__ out) {
    int tid = threadIdx.x;  // 512 = 64 graphs * 8 classes
    int g = tid >> 3, k = tid & 7;
    float cnt = (float)(gend[g] - gstart[g]);
    float inv = 1.0f / fmaxf(cnt, 1.0f);
    float acc = 0.f;
    for (int c = 0; c < 128; ++c)
        acc += (sums[(size_t)g * 128 + c] * inv + b2[c]) * linW[(size_t)c * 8 + k];
    out[(size_t)g * 8 + k] = acc + linb[k];
}

// ---------------- launch ----------------

extern "C" void kernel_launch(void* const* d_in, const int* in_sizes, int n_in,
                              void* d_out, int out_size, void* d_ws, size_t ws_size,
                              hipStream_t stream) {
    const float* x     = (const float*)d_in[0];
    const int*   ei    = (const int*)d_in[1];  // [2,E]: src = ei, dst = ei+E
    const int*   batch = (const int*)d_in[2];
    const float* W1    = (const float*)d_in[3];
    const float* b1    = (const float*)d_in[4];
    const float* W2    = (const float*)d_in[5];
    const float* b2    = (const float*)d_in[6];
    const float* linW  = (const float*)d_in[7];
    const float* linb  = (const float*)d_in[8];
    float* out = (float*)d_out;

    const int N = NNODES, E = NEDGES;
    const int* src = ei;
    const int* dst = ei + E;

    char* ws = (char*)d_ws;
    uint*  bufA16 = (uint*)ws;     ws += (size_t)N * 64 * 4;   // msg (bf16), 25.6MB
    uint*  bufH16 = (uint*)ws;     ws += (size_t)N * 64 * 4;   // h (bf16), 25.6MB
    float* dinv   = (float*)ws;    ws += (size_t)N * 4;
    int*   cnt    = (int*)ws;      ws += (size_t)N * 4;
    int*   offs   = (int*)ws;      ws += (size_t)(N + 1) * 4;
    int*   bsums  = (int*)ws;      ws += 128 * 4;
    int*   csr    = (int*)ws;      ws += (size_t)E * 4;        // 6.4MB
    int*   bcnt   = (int*)ws;      ws += (NB + 1) * 4;
    float* sums   = (float*)ws;    ws += NGRAPHS * 128 * 4;    // contiguous with bcnt (one zero)
    int*   boffs  = (int*)ws;      ws += (NB + 1) * 4;
    int*   bcur   = (int*)ws;      ws += (NB + 1) * 4;
    int*   gstart = (int*)ws;      ws += NGRAPHS * 4;
    int*   gend   = (int*)ws;      ws += NGRAPHS * 4;
    // pairs aliases bufH16: CSR build completes before agg1 writes h1
    uint*  pairs  = (uint*)bufH16;  // 6.4MB < 25.6MB

    const int B = 256;
    const int nScanBlocks = (N + 1023) / 1024;
    const int nzero = (NB + 1) + NGRAPHS * 128;

    k_zero_int<<<(nzero + B - 1) / B, B, 0, stream>>>(bcnt, nzero);

    // CSR build
    k_bcount<<<256, B, 0, stream>>>(dst, bcnt, E);
    k_bscan<<<1, 512, 0, stream>>>(bcnt, boffs, bcur);
    k_bscatter<<<(E + 2047) / 2048, B, 0, stream>>>(src, dst, bcur, pairs, E);
    k_nodecnt<<<NB, B, 0, stream>>>(pairs, boffs, cnt, dinv, N);
    k_scan_local<<<nScanBlocks, B, 0, stream>>>(cnt, offs, bsums, N);
    k_scan_bsums<<<1, B, 0, stream>>>(bsums, nScanBlocks);
    k_scan_add_bounds<<<(N + B - 1) / B, B, 0, stream>>>(offs, bsums, batch, gstart, gend, N);
    k_csr<<<NB, B, 0, stream>>>(pairs, boffs, offs, csr, N);

    const int gemmGrid = (N + 63) / 64;
    const int aggGrid = (N * 64 + B - 1) / B;

    // layer 1
    k_gemm_f32<<<gemmGrid, B, 0, stream>>>(x, W1, dinv, (ushort*)bufA16, N);
    k_agg<<<aggGrid, B, 0, stream>>>((const uint4*)bufA16, dinv, offs, csr, b1,
                                     (uint4*)bufH16, N, 1);

    // layer 2
    k_gemm_b16<<<gemmGrid, B, 0, stream>>>((const ushort*)bufH16, W2, dinv,
                                           (ushort*)bufA16, N);
    k_agg<<<aggGrid, B, 0, stream>>>((const uint4*)bufA16, dinv, offs, csr, nullptr,
                                     (uint4*)bufH16, N, 0);

    // pool + head
    k_pool16<<<dim3(NGRAPHS, 8), 128, 0, stream>>>(bufH16, gstart, gend, sums);
    k_final<<<1, 512, 0, stream>>>(sums, gstart, gend, b2, linW, linb, out);
}

// Round 7
// 307.615 us; speedup vs baseline: 1.0681x; 1.0681x over previous
//
#include <hip/hip_runtime.h>
#include <hip/hip_fp16.h>
#include <cstdint>
#include <cstddef>

#define NNODES 100000
#define NEDGES 1600000
#define NGRAPHS 64
#define BSHIFT 8
#define BRANGE 256
#define NB 391  // ceil(NNODES / 256)

typedef short short8v __attribute__((ext_vector_type(8)));
typedef float float4v __attribute__((ext_vector_type(4)));

__device__ inline short f2h_s(float f) {
    __half h = __float2half(f);
    return __builtin_bit_cast(short, h);
}
__device__ inline ushort f2h_u(float f) {
    __half h = __float2half(f);
    return __builtin_bit_cast(ushort, h);
}
__device__ inline __half2 u2h2(uint u) { return __builtin_bit_cast(__half2, u); }
__device__ inline uint h22u(__half2 h) { return __builtin_bit_cast(uint, h); }

// ---------------- utils ----------------

__global__ void k_zero_int(int* p, int n) {
    int i = blockIdx.x * blockDim.x + threadIdx.x;
    if (i < n) p[i] = 0;
}

// ---------------- CSR build (bucketed, LDS-aggregated) ----------------

__global__ __launch_bounds__(256) void k_bcount(const int* __restrict__ dst,
                                                int* __restrict__ bcnt, int E) {
    __shared__ int h[NB];
    for (int i = threadIdx.x; i < NB; i += 256) h[i] = 0;
    __syncthreads();
    for (int e = blockIdx.x * 256 + threadIdx.x; e < E; e += gridDim.x * 256)
        atomicAdd(&h[dst[e] >> BSHIFT], 1);
    __syncthreads();
    for (int i = threadIdx.x; i < NB; i += 256)
        if (h[i]) atomicAdd(&bcnt[i], h[i]);
}

__global__ __launch_bounds__(512) void k_bscan(const int* __restrict__ bcnt,
                                               int* __restrict__ boffs,
                                               int* __restrict__ bcur) {
    __shared__ int sh[512];
    int t = threadIdx.x;
    int v = t < NB ? bcnt[t] : 0;
    sh[t] = v;
    __syncthreads();
    #pragma unroll
    for (int d = 1; d < 512; d <<= 1) {
        int val = (t >= d) ? sh[t - d] : 0;
        __syncthreads();
        sh[t] += val;
        __syncthreads();
    }
    int excl = sh[t] - v;
    if (t < NB) { boffs[t] = excl; bcur[t] = excl; }
    if (t == NB - 1) boffs[NB] = excl + v;
}

// P1: scatter packed (src | (dst&255)<<24) into bucket-grouped order.
#define P1_EPT 8
__global__ __launch_bounds__(256) void k_bscatter(const int* __restrict__ src,
                                                  const int* __restrict__ dst,
                                                  int* __restrict__ bcur,
                                                  uint* __restrict__ pairs, int E) {
    __shared__ int h[NB];
    __shared__ int base[NB];
    int t = threadIdx.x;
    long long c0 = (long long)blockIdx.x * 2048;
    if (c0 >= E) return;
    for (int i = t; i < NB; i += 256) h[i] = 0;
    __syncthreads();
    int myb[P1_EPT], mylp[P1_EPT];
    uint myv[P1_EPT];
    #pragma unroll
    for (int k = 0; k < P1_EPT; ++k) {
        long long e = c0 + t + k * 256;
        if (e < E) {
            int d = dst[e];
            myv[k] = (uint)src[e] | ((uint)(d & (BRANGE - 1)) << 24);
            myb[k] = d >> BSHIFT;
            mylp[k] = atomicAdd(&h[myb[k]], 1);
        } else myb[k] = -1;
    }
    __syncthreads();
    for (int i = t; i < NB; i += 256)
        base[i] = h[i] ? atomicAdd(&bcur[i], h[i]) : 0;
    __syncthreads();
    #pragma unroll
    for (int k = 0; k < P1_EPT; ++k)
        if (myb[k] >= 0) pairs[base[myb[k]] + mylp[k]] = myv[k];
}

// per-bucket node in-degree histogram + dinv (fused)
__global__ __launch_bounds__(256) void k_nodecnt(const uint* __restrict__ pairs,
                                                 const int* __restrict__ boffs,
                                                 int* __restrict__ cnt,
                                                 float* __restrict__ dinv, int N) {
    __shared__ int h[BRANGE];
    int b = blockIdx.x, t = threadIdx.x;
    h[t] = 0;
    __syncthreads();
    int p0 = boffs[b], p1 = boffs[b + 1];
    for (int p = p0 + t; p < p1; p += 256)
        atomicAdd(&h[pairs[p] >> 24], 1);
    __syncthreads();
    int node = (b << BSHIFT) + t;
    if (node < N) {
        cnt[node] = h[t];
        dinv[node] = rsqrtf((float)(h[t] + 1));
    }
}

__global__ __launch_bounds__(256) void k_csr(const uint* __restrict__ pairs,
                                             const int* __restrict__ boffs,
                                             const int* __restrict__ offs,
                                             int* __restrict__ csr, int N) {
    __shared__ int cur[BRANGE];
    int b = blockIdx.x, t = threadIdx.x;
    int node = (b << BSHIFT) + t;
    cur[t] = node < N ? offs[node] : 0;
    __syncthreads();
    int p0 = boffs[b], p1 = boffs[b + 1];
    for (int p = p0 + t; p < p1; p += 256) {
        uint pr = pairs[p];
        int pos = atomicAdd(&cur[pr >> 24], 1);
        csr[pos] = (int)(pr & 0x00FFFFFFu);
    }
}

// ---------------- node-count exclusive scan ----------------

__global__ __launch_bounds__(256) void k_scan_local(const int* __restrict__ cnt,
                                                    int* __restrict__ offs,
                                                    int* __restrict__ bsums, int n) {
    __shared__ int sh[256];
    int t = threadIdx.x;
    int base = blockIdx.x * 1024 + t * 4;
    int v0 = base + 0 < n ? cnt[base + 0] : 0;
    int v1 = base + 1 < n ? cnt[base + 1] : 0;
    int v2 = base + 2 < n ? cnt[base + 2] : 0;
    int v3 = base + 3 < n ? cnt[base + 3] : 0;
    int tsum = v0 + v1 + v2 + v3;
    sh[t] = tsum;
    __syncthreads();
    #pragma unroll
    for (int d = 1; d < 256; d <<= 1) {
        int val = (t >= d) ? sh[t - d] : 0;
        __syncthreads();
        sh[t] += val;
        __syncthreads();
    }
    int excl = sh[t] - tsum;
    if (t == 255) bsums[blockIdx.x] = sh[255];
    if (base + 0 < n) offs[base + 0] = excl;
    if (base + 1 < n) offs[base + 1] = excl + v0;
    if (base + 2 < n) offs[base + 2] = excl + v0 + v1;
    if (base + 3 < n) offs[base + 3] = excl + v0 + v1 + v2;
}

__global__ __launch_bounds__(256) void k_scan_bsums(int* bsums, int nb) {
    __shared__ int sh[256];
    int t = threadIdx.x;
    int v = t < nb ? bsums[t] : 0;
    sh[t] = v;
    __syncthreads();
    #pragma unroll
    for (int d = 1; d < 256; d <<= 1) {
        int val = (t >= d) ? sh[t - d] : 0;
        __syncthreads();
        sh[t] += val;
        __syncthreads();
    }
    if (t < nb) bsums[t] = sh[t] - v;
}

// scan finalize + graph segment bounds (fused)
__global__ void k_scan_add_bounds(int* __restrict__ offs, const int* __restrict__ bsums,
                                  const int* __restrict__ batch, int* __restrict__ gstart,
                                  int* __restrict__ gend, int n) {
    int i = blockIdx.x * blockDim.x + threadIdx.x;
    if (i < n) {
        offs[i] += bsums[i >> 10];
        int b = batch[i];
        if (i == 0 || batch[i - 1] != b) gstart[b] = i;
        if (i == n - 1 || batch[i + 1] != b) gend[b] = i + 1;
    }
    if (i == 0) offs[n] = NEDGES;
}

// ---------------- MFMA GEMM (f16): msg[n,128] = (X[n,128] @ W[128,128]) * dinv[row] ----

__global__ __launch_bounds__(256) void k_gemm_f32(const float* __restrict__ X,
                                                  const float* __restrict__ W,
                                                  const float* __restrict__ dinv,
                                                  ushort* __restrict__ Y, int nrows) {
    __shared__ short8v sW[2048];  // [kk(4)][ct(8)][lane(64)]
    const int tid = threadIdx.x;
    const int lane = tid & 63;
    const int w = tid >> 6;

    for (int s = tid; s < 2048; s += 256) {
        int p = s >> 6, l = s & 63;
        int kk = p >> 3, ct = p & 7;
        int kb = kk * 32 + (l >> 4) * 8;
        int j = ct * 16 + (l & 15);
        short8v v;
        #pragma unroll
        for (int i = 0; i < 8; ++i)
            v[i] = f2h_s(W[(size_t)(kb + i) * 128 + j]);
        sW[s] = v;
    }
    __syncthreads();

    const int row0 = blockIdx.x * 64 + w * 16;
    const int arow = row0 + (lane & 15);
    float4v acc[8];
    #pragma unroll
    for (int ct = 0; ct < 8; ++ct) acc[ct] = (float4v)0.f;

    #pragma unroll
    for (int kk = 0; kk < 4; ++kk) {
        short8v a = (short8v)0;
        if (arow < nrows) {
            const float* xp = X + (size_t)arow * 128 + kk * 32 + ((lane >> 4) * 8);
            float4 f0 = ((const float4*)xp)[0];
            float4 f1 = ((const float4*)xp)[1];
            a[0] = f2h_s(f0.x); a[1] = f2h_s(f0.y);
            a[2] = f2h_s(f0.z); a[3] = f2h_s(f0.w);
            a[4] = f2h_s(f1.x); a[5] = f2h_s(f1.y);
            a[6] = f2h_s(f1.z); a[7] = f2h_s(f1.w);
        }
        #pragma unroll
        for (int ct = 0; ct < 8; ++ct)
            acc[ct] = __builtin_amdgcn_mfma_f32_16x16x32_f16(a, sW[(kk * 8 + ct) * 64 + lane],
                                                             acc[ct], 0, 0, 0);
    }

    const int orow = row0 + ((lane >> 4) << 2);
    #pragma unroll
    for (int r = 0; r < 4; ++r) {
        int row = orow + r;
        if (row < nrows) {
            float dr = dinv[row];
            #pragma unroll
            for (int ct = 0; ct < 8; ++ct)
                Y[(size_t)row * 128 + ct * 16 + (lane & 15)] = f2h_u(acc[ct][r] * dr);
        }
    }
}

// fp16-input variant (layer 2): A fragments load directly
__global__ __launch_bounds__(256) void k_gemm_h16(const ushort* __restrict__ X,
                                                  const float* __restrict__ W,
                                                  const float* __restrict__ dinv,
                                                  ushort* __restrict__ Y, int nrows) {
    __shared__ short8v sW[2048];
    const int tid = threadIdx.x;
    const int lane = tid & 63;
    const int w = tid >> 6;

    for (int s = tid; s < 2048; s += 256) {
        int p = s >> 6, l = s & 63;
        int kk = p >> 3, ct = p & 7;
        int kb = kk * 32 + (l >> 4) * 8;
        int j = ct * 16 + (l & 15);
        short8v v;
        #pragma unroll
        for (int i = 0; i < 8; ++i)
            v[i] = f2h_s(W[(size_t)(kb + i) * 128 + j]);
        sW[s] = v;
    }
    __syncthreads();

    const int row0 = blockIdx.x * 64 + w * 16;
    const int arow = row0 + (lane & 15);
    float4v acc[8];
    #pragma unroll
    for (int ct = 0; ct < 8; ++ct) acc[ct] = (float4v)0.f;

    #pragma unroll
    for (int kk = 0; kk < 4; ++kk) {
        short8v a = (short8v)0;
        if (arow < nrows)
            a = *(const short8v*)(X + (size_t)arow * 128 + kk * 32 + ((lane >> 4) * 8));
        #pragma unroll
        for (int ct = 0; ct < 8; ++ct)
            acc[ct] = __builtin_amdgcn_mfma_f32_16x16x32_f16(a, sW[(kk * 8 + ct) * 64 + lane],
                                                             acc[ct], 0, 0, 0);
    }

    const int orow = row0 + ((lane >> 4) << 2);
    #pragma unroll
    for (int r = 0; r < 4; ++r) {
        int row = orow + r;
        if (row < nrows) {
            float dr = dinv[row];
            #pragma unroll
            for (int ct = 0; ct < 8; ++ct)
                Y[(size_t)row * 128 + ct * 16 + (lane & 15)] = f2h_u(acc[ct][r] * dr);
        }
    }
}

// ---------------- CSR aggregation: wave/node, fp16 packed adds ----------------
// h[i,:] = relu( dinv[i] * (msg[i,:] + sum_{s in in(i)} msg[s,:]) + bias )
// lane holds channels {2*lane, 2*lane+1}; msg pre-scaled by dinv[src].

__global__ __launch_bounds__(256) void k_agg(const uint* __restrict__ msg,
                                             const float* __restrict__ dinv,
                                             const int* __restrict__ offs,
                                             const int* __restrict__ csr,
                                             const float* __restrict__ bias,
                                             uint* __restrict__ outb, int n, int dorelu) {
    int wid = (int)((blockIdx.x * 256 + threadIdx.x) >> 6);
    if (wid >= n) return;
    const int lane = threadIdx.x & 63;
    __half2 acc = u2h2(msg[(size_t)wid * 64 + lane]);  // self contribution
    const int e0 = offs[wid], e1 = offs[wid + 1];
    for (int e = e0; e < e1; e += 64) {
        int me = e + lane;
        int sidx = 0;
        if (me < e1) sidx = csr[me];
        int cnt = min(64, e1 - e);
        int k = 0;
        for (; k + 2 <= cnt; k += 2) {
            int s0 = __shfl(sidx, k);
            int s1 = __shfl(sidx, k + 1);
            __half2 u0 = u2h2(msg[(size_t)s0 * 64 + lane]);
            __half2 u1 = u2h2(msg[(size_t)s1 * 64 + lane]);
            acc = __hadd2(acc, u0);
            acc = __hadd2(acc, u1);
        }
        if (k < cnt) {
            int s0 = __shfl(sidx, k);
            acc = __hadd2(acc, u2h2(msg[(size_t)s0 * 64 + lane]));
        }
    }
    float2 f = __half22float2(acc);
    float dd = dinv[wid];
    float ax = f.x * dd, ay = f.y * dd;
    if (bias) {
        ax += bias[lane * 2];
        ay += bias[lane * 2 + 1];
        if (dorelu) { ax = fmaxf(ax, 0.f); ay = fmaxf(ay, 0.f); }
    }
    outb[(size_t)wid * 64 + lane] = h22u(__floats2half2_rn(ax, ay));
}

// ---------------- pooling (fp16 input) ----------------

__global__ __launch_bounds__(128) void k_pool16(const uint* __restrict__ buf,
                                                const int* __restrict__ gstart,
                                                const int* __restrict__ gend,
                                                float* __restrict__ sums) {
    int g = blockIdx.x, chunk = blockIdx.y;
    int s = gstart[g], e = gend[g];
    int per = (e - s + 7) >> 3;
    int r0 = s + chunk * per, r1 = min(e, r0 + per);
    int j = threadIdx.x & 63, half = threadIdx.x >> 6;
    float ax = 0.f, ay = 0.f;
    for (int r = r0 + half; r < r1; r += 2) {
        float2 f = __half22float2(u2h2(buf[(size_t)r * 64 + j]));
        ax += f.x;
        ay += f.y;
    }
    atomicAdd(&sums[g * 128 + 2 * j], ax);
    atomicAdd(&sums[g * 128 + 2 * j + 1], ay);
}

__global__ void k_final(const float* __restrict__ sums, const int* __restrict__ gstart,
                        const int* __restrict__ gend, const float* __restrict__ b2,
                        const float* __restrict__ linW, const float* __restrict__ linb,
                        float* __restrict__ out) {
    int tid = threadIdx.x;  // 512 = 64 graphs * 8 classes
    int g = tid >> 3, k = tid & 7;
    float cnt = (float)(gend[g] - gstart[g]);
    float inv = 1.0f / fmaxf(cnt, 1.0f);
    float acc = 0.f;
    for (int c = 0; c < 128; ++c)
        acc += (sums[(size_t)g * 128 + c] * inv + b2[c]) * linW[(size_t)c * 8 + k];
    out[(size_t)g * 8 + k] = acc + linb[k];
}

// ---------------- launch ----------------

extern "C" void kernel_launch(void* const* d_in, const int* in_sizes, int n_in,
                              void* d_out, int out_size, void* d_ws, size_t ws_size,
                              hipStream_t stream) {
    const float* x     = (const float*)d_in[0];
    const int*   ei    = (const int*)d_in[1];  // [2,E]: src = ei, dst = ei+E
    const int*   batch = (const int*)d_in[2];
    const float* W1    = (const float*)d_in[3];
    const float* b1    = (const float*)d_in[4];
    const float* W2    = (const float*)d_in[5];
    const float* b2    = (const float*)d_in[6];
    const float* linW  = (const float*)d_in[7];
    const float* linb  = (const float*)d_in[8];
    float* out = (float*)d_out;

    const int N = NNODES, E = NEDGES;
    const int* src = ei;
    const int* dst = ei + E;

    char* ws = (char*)d_ws;
    uint*  bufA16 = (uint*)ws;     ws += (size_t)N * 64 * 4;   // msg (fp16), 25.6MB
    uint*  bufH16 = (uint*)ws;     ws += (size_t)N * 64 * 4;   // h (fp16), 25.6MB
    float* dinv   = (float*)ws;    ws += (size_t)N * 4;
    int*   cnt    = (int*)ws;      ws += (size_t)N * 4;
    int*   offs   = (int*)ws;      ws += (size_t)(N + 1) * 4;
    int*   bsums  = (int*)ws;      ws += 128 * 4;
    int*   csr    = (int*)ws;      ws += (size_t)E * 4;        // 6.4MB
    int*   bcnt   = (int*)ws;      ws += (NB + 1) * 4;
    float* sums   = (float*)ws;    ws += NGRAPHS * 128 * 4;    // contiguous with bcnt (one zero)
    int*   boffs  = (int*)ws;      ws += (NB + 1) * 4;
    int*   bcur   = (int*)ws;      ws += (NB + 1) * 4;
    int*   gstart = (int*)ws;      ws += NGRAPHS * 4;
    int*   gend   = (int*)ws;      ws += NGRAPHS * 4;
    // pairs aliases bufH16: CSR build completes before agg1 writes h1
    uint*  pairs  = (uint*)bufH16;  // 6.4MB < 25.6MB

    const int B = 256;
    const int nScanBlocks = (N + 1023) / 1024;
    const int nzero = (NB + 1) + NGRAPHS * 128;

    k_zero_int<<<(nzero + B - 1) / B, B, 0, stream>>>(bcnt, nzero);

    // CSR build
    k_bcount<<<256, B, 0, stream>>>(dst, bcnt, E);
    k_bscan<<<1, 512, 0, stream>>>(bcnt, boffs, bcur);
    k_bscatter<<<(E + 2047) / 2048, B, 0, stream>>>(src, dst, bcur, pairs, E);
    k_nodecnt<<<NB, B, 0, stream>>>(pairs, boffs, cnt, dinv, N);
    k_scan_local<<<nScanBlocks, B, 0, stream>>>(cnt, offs, bsums, N);
    k_scan_bsums<<<1, B, 0, stream>>>(bsums, nScanBlocks);
    k_scan_add_bounds<<<(N + B - 1) / B, B, 0, stream>>>(offs, bsums, batch, gstart, gend, N);
    k_csr<<<NB, B, 0, stream>>>(pairs, boffs, offs, csr, N);

    const int gemmGrid = (N + 63) / 64;
    const int aggGrid = (N * 64 + B - 1) / B;

    // layer 1
    k_gemm_f32<<<gemmGrid, B, 0, stream>>>(x, W1, dinv, (ushort*)bufA16, N);
    k_agg<<<aggGrid, B, 0, stream>>>(bufA16, dinv, offs, csr, b1, bufH16, N, 1);

    // layer 2
    k_gemm_h16<<<gemmGrid, B, 0, stream>>>((const ushort*)bufH16, W2, dinv,
                                           (ushort*)bufA16, N);
    k_agg<<<aggGrid, B, 0, stream>>>(bufA16, dinv, offs, csr, nullptr, bufH16, N, 0);

    // pool + head
    k_pool16<<<dim3(NGRAPHS, 8), 128, 0, stream>>>(bufH16, gstart, gend, sums);
    k_final<<<1, 512, 0, stream>>>(sums, gstart, gend, b2, linW, linb, out);
}

// Round 8
// 291.816 us; speedup vs baseline: 1.1259x; 1.0541x over previous
//
#include <hip/hip_runtime.h>
#include <hip/hip_fp16.h>
#include <cstdint>
#include <cstddef>

#define NNODES 100000
#define NEDGES 1600000
#define NGRAPHS 64
#define BSHIFT 7
#define BRANGE 128
#define NB 782  // ceil(NNODES / 128)

typedef short short8v __attribute__((ext_vector_type(8)));
typedef float float4v __attribute__((ext_vector_type(4)));

__device__ inline short f2h_s(float f) {
    __half h = __float2half(f);
    return __builtin_bit_cast(short, h);
}
__device__ inline ushort f2h_u(float f) {
    __half h = __float2half(f);
    return __builtin_bit_cast(ushort, h);
}
__device__ inline __half2 u2h2(uint u) { return __builtin_bit_cast(__half2, u); }
__device__ inline uint h22u(__half2 h) { return __builtin_bit_cast(uint, h); }

// ---------------- utils ----------------

__global__ void k_zero_int(int* p, int n) {
    int i = blockIdx.x * blockDim.x + threadIdx.x;
    if (i < n) p[i] = 0;
}

// W[128,128] f32 -> fragment-ordered fp16: out[s], s = (kk*8+ct)*64+lane,
// elem i = W[kk*32+(lane>>4)*8+i][ct*16+(lane&15)]
__global__ __launch_bounds__(256) void k_prepw(const float* __restrict__ W1,
                                               const float* __restrict__ W2,
                                               short8v* __restrict__ o1,
                                               short8v* __restrict__ o2) {
    const float* W = blockIdx.x ? W2 : W1;
    short8v* o = blockIdx.x ? o2 : o1;
    for (int s = threadIdx.x; s < 2048; s += 256) {
        int p = s >> 6, l = s & 63;
        int kb = (p >> 3) * 32 + ((l >> 4) * 8);
        int j = (p & 7) * 16 + (l & 15);
        short8v v;
        #pragma unroll
        for (int i = 0; i < 8; ++i)
            v[i] = f2h_s(W[(size_t)(kb + i) * 128 + j]);
        o[s] = v;
    }
}

// ---------------- CSR build (bucketed, LDS-aggregated) ----------------

__global__ __launch_bounds__(256) void k_bcount(const int* __restrict__ dst,
                                                int* __restrict__ bcnt, int E) {
    __shared__ int h[NB];
    for (int i = threadIdx.x; i < NB; i += 256) h[i] = 0;
    __syncthreads();
    for (int e = blockIdx.x * 256 + threadIdx.x; e < E; e += gridDim.x * 256)
        atomicAdd(&h[dst[e] >> BSHIFT], 1);
    __syncthreads();
    for (int i = threadIdx.x; i < NB; i += 256)
        if (h[i]) atomicAdd(&bcnt[i], h[i]);
}

__global__ __launch_bounds__(1024) void k_bscan(const int* __restrict__ bcnt,
                                                int* __restrict__ boffs,
                                                int* __restrict__ bcur) {
    __shared__ int sh[1024];
    int t = threadIdx.x;
    int v = t < NB ? bcnt[t] : 0;
    sh[t] = v;
    __syncthreads();
    #pragma unroll
    for (int d = 1; d < 1024; d <<= 1) {
        int val = (t >= d) ? sh[t - d] : 0;
        __syncthreads();
        sh[t] += val;
        __syncthreads();
    }
    int excl = sh[t] - v;
    if (t < NB) { boffs[t] = excl; bcur[t] = excl; }
    if (t == NB - 1) boffs[NB] = excl + v;
}

// P1: scatter packed (src | (dst&127)<<24) into bucket-grouped order.
#define P1_EPT 8
__global__ __launch_bounds__(256) void k_bscatter(const int* __restrict__ src,
                                                  const int* __restrict__ dst,
                                                  int* __restrict__ bcur,
                                                  uint* __restrict__ pairs, int E) {
    __shared__ int h[NB];
    __shared__ int base[NB];
    int t = threadIdx.x;
    long long c0 = (long long)blockIdx.x * 2048;
    if (c0 >= E) return;
    for (int i = t; i < NB; i += 256) h[i] = 0;
    __syncthreads();
    int myb[P1_EPT], mylp[P1_EPT];
    uint myv[P1_EPT];
    #pragma unroll
    for (int k = 0; k < P1_EPT; ++k) {
        long long e = c0 + t + k * 256;
        if (e < E) {
            int d = dst[e];
            myv[k] = (uint)src[e] | ((uint)(d & (BRANGE - 1)) << 24);
            myb[k] = d >> BSHIFT;
            mylp[k] = atomicAdd(&h[myb[k]], 1);
        } else myb[k] = -1;
    }
    __syncthreads();
    for (int i = t; i < NB; i += 256)
        base[i] = h[i] ? atomicAdd(&bcur[i], h[i]) : 0;
    __syncthreads();
    #pragma unroll
    for (int k = 0; k < P1_EPT; ++k)
        if (myb[k] >= 0) pairs[base[myb[k]] + mylp[k]] = myv[k];
}

// Fused per-bucket: node histogram -> dinv + offs (via boffs[b] + local scan) -> CSR scatter
__global__ __launch_bounds__(256) void k_build(const uint* __restrict__ pairs,
                                               const int* __restrict__ boffs,
                                               int* __restrict__ offs,
                                               float* __restrict__ dinv,
                                               int* __restrict__ csr, int N) {
    __shared__ int h[256];
    __shared__ int sh[256];
    __shared__ int cur[BRANGE];
    int b = blockIdx.x, t = threadIdx.x;
    h[t] = 0;
    __syncthreads();
    int p0 = boffs[b], p1 = boffs[b + 1];
    for (int p = p0 + t; p < p1; p += 256)
        atomicAdd(&h[pairs[p] >> 24], 1);
    __syncthreads();
    int myh = h[t];
    sh[t] = myh;
    __syncthreads();
    #pragma unroll
    for (int d = 1; d < 256; d <<= 1) {
        int val = (t >= d) ? sh[t - d] : 0;
        __syncthreads();
        sh[t] += val;
        __syncthreads();
    }
    int excl = sh[t] - myh;   // exclusive scan (bins >=128 are zero)
    int node = (b << BSHIFT) + t;
    if (t < BRANGE) {
        cur[t] = p0 + excl;
        if (node < N) {
            offs[node] = p0 + excl;
            dinv[node] = rsqrtf((float)(myh + 1));
        }
    }
    if (b == 0 && t == 0) offs[N] = NEDGES;
    __syncthreads();
    for (int p = p0 + t; p < p1; p += 256) {
        uint pr = pairs[p];
        int pos = atomicAdd(&cur[pr >> 24], 1);
        csr[pos] = (int)(pr & 0x00FFFFFFu);
    }
}

// graph segment bounds (batch sorted)
__global__ void k_bounds(const int* __restrict__ batch, int* __restrict__ gstart,
                         int* __restrict__ gend, int n) {
    int i = blockIdx.x * blockDim.x + threadIdx.x;
    if (i >= n) return;
    int b = batch[i];
    if (i == 0 || batch[i - 1] != b) gstart[b] = i;
    if (i == n - 1 || batch[i + 1] != b) gend[b] = i + 1;
}

// ---------------- MFMA GEMM (f16): msg[n,128] = (X[n,128] @ W[128,128]) * dinv[row] ----

__global__ __launch_bounds__(256) void k_gemm_f32(const float* __restrict__ X,
                                                  const short8v* __restrict__ wf,
                                                  const float* __restrict__ dinv,
                                                  ushort* __restrict__ Y, int nrows) {
    __shared__ short8v sW[2048];
    const int tid = threadIdx.x;
    const int lane = tid & 63;
    const int w = tid >> 6;

    for (int s = tid; s < 2048; s += 256) sW[s] = wf[s];
    __syncthreads();

    const int row0 = blockIdx.x * 64 + w * 16;
    const int arow = row0 + (lane & 15);
    float4v acc[8];
    #pragma unroll
    for (int ct = 0; ct < 8; ++ct) acc[ct] = (float4v)0.f;

    #pragma unroll
    for (int kk = 0; kk < 4; ++kk) {
        short8v a = (short8v)0;
        if (arow < nrows) {
            const float* xp = X + (size_t)arow * 128 + kk * 32 + ((lane >> 4) * 8);
            float4 f0 = ((const float4*)xp)[0];
            float4 f1 = ((const float4*)xp)[1];
            a[0] = f2h_s(f0.x); a[1] = f2h_s(f0.y);
            a[2] = f2h_s(f0.z); a[3] = f2h_s(f0.w);
            a[4] = f2h_s(f1.x); a[5] = f2h_s(f1.y);
            a[6] = f2h_s(f1.z); a[7] = f2h_s(f1.w);
        }
        #pragma unroll
        for (int ct = 0; ct < 8; ++ct)
            acc[ct] = __builtin_amdgcn_mfma_f32_16x16x32_f16(a, sW[(kk * 8 + ct) * 64 + lane],
                                                             acc[ct], 0, 0, 0);
    }

    const int orow = row0 + ((lane >> 4) << 2);
    #pragma unroll
    for (int r = 0; r < 4; ++r) {
        int row = orow + r;
        if (row < nrows) {
            float dr = dinv[row];
            #pragma unroll
            for (int ct = 0; ct < 8; ++ct)
                Y[(size_t)row * 128 + ct * 16 + (lane & 15)] = f2h_u(acc[ct][r] * dr);
        }
    }
}

// fp16-input variant (layer 2): A fragments load directly
__global__ __launch_bounds__(256) void k_gemm_h16(const ushort* __restrict__ X,
                                                  const short8v* __restrict__ wf,
                                                  const float* __restrict__ dinv,
                                                  ushort* __restrict__ Y, int nrows) {
    __shared__ short8v sW[2048];
    const int tid = threadIdx.x;
    const int lane = tid & 63;
    const int w = tid >> 6;

    for (int s = tid; s < 2048; s += 256) sW[s] = wf[s];
    __syncthreads();

    const int row0 = blockIdx.x * 64 + w * 16;
    const int arow = row0 + (lane & 15);
    float4v acc[8];
    #pragma unroll
    for (int ct = 0; ct < 8; ++ct) acc[ct] = (float4v)0.f;

    #pragma unroll
    for (int kk = 0; kk < 4; ++kk) {
        short8v a = (short8v)0;
        if (arow < nrows)
            a = *(const short8v*)(X + (size_t)arow * 128 + kk * 32 + ((lane >> 4) * 8));
        #pragma unroll
        for (int ct = 0; ct < 8; ++ct)
            acc[ct] = __builtin_amdgcn_mfma_f32_16x16x32_f16(a, sW[(kk * 8 + ct) * 64 + lane],
                                                             acc[ct], 0, 0, 0);
    }

    const int orow = row0 + ((lane >> 4) << 2);
    #pragma unroll
    for (int r = 0; r < 4; ++r) {
        int row = orow + r;
        if (row < nrows) {
            float dr = dinv[row];
            #pragma unroll
            for (int ct = 0; ct < 8; ++ct)
                Y[(size_t)row * 128 + ct * 16 + (lane & 15)] = f2h_u(acc[ct][r] * dr);
        }
    }
}

// ---------------- CSR aggregation: wave/node, fp16 packed adds, 4-deep ----------------
// h[i,:] = relu( dinv[i] * (msg[i,:] + sum_{s in in(i)} msg[s,:]) + bias )

__global__ __launch_bounds__(256) void k_agg(const uint* __restrict__ msg,
                                             const float* __restrict__ dinv,
                                             const int* __restrict__ offs,
                                             const int* __restrict__ csr,
                                             const float* __restrict__ bias,
                                             uint* __restrict__ outb, int n, int dorelu) {
    int wid = (int)((blockIdx.x * 256 + threadIdx.x) >> 6);
    if (wid >= n) return;
    const int lane = threadIdx.x & 63;
    __half2 a0 = u2h2(msg[(size_t)wid * 64 + lane]);  // self contribution
    __half2 a1 = u2h2(0u);
    const int e0 = offs[wid], e1 = offs[wid + 1];
    for (int e = e0; e < e1; e += 64) {
        int me = e + lane;
        int sidx = (me < e1) ? csr[me] : 0;
        int cnt = min(64, e1 - e);
        int k = 0;
        for (; k + 4 <= cnt; k += 4) {
            int s0 = __shfl(sidx, k);
            int s1 = __shfl(sidx, k + 1);
            int s2 = __shfl(sidx, k + 2);
            int s3 = __shfl(sidx, k + 3);
            uint u0 = msg[(size_t)s0 * 64 + lane];
            uint u1 = msg[(size_t)s1 * 64 + lane];
            uint u2 = msg[(size_t)s2 * 64 + lane];
            uint u3 = msg[(size_t)s3 * 64 + lane];
            a0 = __hadd2(a0, u2h2(u0));
            a1 = __hadd2(a1, u2h2(u1));
            a0 = __hadd2(a0, u2h2(u2));
            a1 = __hadd2(a1, u2h2(u3));
        }
        for (; k < cnt; ++k) {
            int s0 = __shfl(sidx, k);
            a0 = __hadd2(a0, u2h2(msg[(size_t)s0 * 64 + lane]));
        }
    }
    __half2 acc = __hadd2(a0, a1);
    float2 f = __half22float2(acc);
    float dd = dinv[wid];
    float ax = f.x * dd, ay = f.y * dd;
    if (bias) {
        ax += bias[lane * 2];
        ay += bias[lane * 2 + 1];
        if (dorelu) { ax = fmaxf(ax, 0.f); ay = fmaxf(ay, 0.f); }
    }
    outb[(size_t)wid * 64 + lane] = h22u(__floats2half2_rn(ax, ay));
}

// ---------------- pooling (fp16 input) ----------------

__global__ __launch_bounds__(128) void k_pool16(const uint* __restrict__ buf,
                                                const int* __restrict__ gstart,
                                                const int* __restrict__ gend,
                                                float* __restrict__ sums) {
    int g = blockIdx.x, chunk = blockIdx.y;
    int s = gstart[g], e = gend[g];
    int per = (e - s + 7) >> 3;
    int r0 = s + chunk * per, r1 = min(e, r0 + per);
    int j = threadIdx.x & 63, half = threadIdx.x >> 6;
    float ax = 0.f, ay = 0.f;
    for (int r = r0 + half; r < r1; r += 2) {
        float2 f = __half22float2(u2h2(buf[(size_t)r * 64 + j]));
        ax += f.x;
        ay += f.y;
    }
    atomicAdd(&sums[g * 128 + 2 * j], ax);
    atomicAdd(&sums[g * 128 + 2 * j + 1], ay);
}

__global__ void k_final(const float* __restrict__ sums, const int* __restrict__ gstart,
                        const int* __restrict__ gend, const float* __restrict__ b2,
                        const float* __restrict__ linW, const float* __restrict__ linb,
                        float* __restrict__ out) {
    int tid = threadIdx.x;  // 512 = 64 graphs * 8 classes
    int g = tid >> 3, k = tid & 7;
    float cnt = (float)(gend[g] - gstart[g]);
    float inv = 1.0f / fmaxf(cnt, 1.0f);
    float acc = 0.f;
    for (int c = 0; c < 128; ++c)
        acc += (sums[(size_t)g * 128 + c] * inv + b2[c]) * linW[(size_t)c * 8 + k];
    out[(size_t)g * 8 + k] = acc + linb[k];
}

// ---------------- launch ----------------

extern "C" void kernel_launch(void* const* d_in, const int* in_sizes, int n_in,
                              void* d_out, int out_size, void* d_ws, size_t ws_size,
                              hipStream_t stream) {
    const float* x     = (const float*)d_in[0];
    const int*   ei    = (const int*)d_in[1];  // [2,E]: src = ei, dst = ei+E
    const int*   batch = (const int*)d_in[2];
    const float* W1    = (const float*)d_in[3];
    const float* b1    = (const float*)d_in[4];
    const float* W2    = (const float*)d_in[5];
    const float* b2    = (const float*)d_in[6];
    const float* linW  = (const float*)d_in[7];
    const float* linb  = (const float*)d_in[8];
    float* out = (float*)d_out;

    const int N = NNODES, E = NEDGES;
    const int* src = ei;
    const int* dst = ei + E;

    char* ws = (char*)d_ws;
    uint*  bufA16 = (uint*)ws;     ws += (size_t)N * 64 * 4;   // msg (fp16), 25.6MB
    uint*  bufH16 = (uint*)ws;     ws += (size_t)N * 64 * 4;   // h (fp16), 25.6MB
    float* dinv   = (float*)ws;    ws += (size_t)N * 4;
    int*   offs   = (int*)ws;      ws += (size_t)(N + 1) * 4;
    int*   csr    = (int*)ws;      ws += (size_t)E * 4;        // 6.4MB
    int*   bcnt   = (int*)ws;      ws += NB * 4;
    float* sums   = (float*)ws;    ws += NGRAPHS * 128 * 4;    // contiguous with bcnt (one zero)
    int*   boffs  = (int*)ws;      ws += (NB + 1) * 4;
    int*   bcur   = (int*)ws;      ws += NB * 4;
    int*   gstart = (int*)ws;      ws += NGRAPHS * 4;
    int*   gend   = (int*)ws;      ws += NGRAPHS * 4;
    short8v* wf1  = (short8v*)ws;  ws += 2048 * 16;            // 32KB fragment-ordered W1
    short8v* wf2  = (short8v*)ws;  ws += 2048 * 16;            // 32KB fragment-ordered W2
    // pairs aliases bufH16: CSR build completes before agg1 writes h1
    uint*  pairs  = (uint*)bufH16;  // 6.4MB < 25.6MB

    const int B = 256;
    const int nzero = NB + NGRAPHS * 128;

    k_zero_int<<<(nzero + B - 1) / B, B, 0, stream>>>(bcnt, nzero);
    k_prepw<<<2, B, 0, stream>>>(W1, W2, wf1, wf2);

    // CSR build
    k_bcount<<<256, B, 0, stream>>>(dst, bcnt, E);
    k_bscan<<<1, 1024, 0, stream>>>(bcnt, boffs, bcur);
    k_bscatter<<<(E + 2047) / 2048, B, 0, stream>>>(src, dst, bcur, pairs, E);
    k_build<<<NB, B, 0, stream>>>(pairs, boffs, offs, dinv, csr, N);
    k_bounds<<<(N + B - 1) / B, B, 0, stream>>>(batch, gstart, gend, N);

    const int gemmGrid = (N + 63) / 64;
    const int aggGrid = (N * 64 + B - 1) / B;

    // layer 1
    k_gemm_f32<<<gemmGrid, B, 0, stream>>>(x, wf1, dinv, (ushort*)bufA16, N);
    k_agg<<<aggGrid, B, 0, stream>>>(bufA16, dinv, offs, csr, b1, bufH16, N, 1);

    // layer 2
    k_gemm_h16<<<gemmGrid, B, 0, stream>>>((const ushort*)bufH16, wf2, dinv,
                                           (ushort*)bufA16, N);
    k_agg<<<aggGrid, B, 0, stream>>>(bufA16, dinv, offs, csr, nullptr, bufH16, N, 0);

    // pool + head
    k_pool16<<<dim3(NGRAPHS, 8), 128, 0, stream>>>(bufH16, gstart, gend, sums);
    k_final<<<1, 512, 0, stream>>>(sums, gstart, gend, b2, linW, linb, out);
}